// Round 5
// baseline (227.123 us; speedup 1.0000x reference)
//
#include <hip/hip_runtime.h>

#define DEV __device__ __forceinline__

typedef __attribute__((ext_vector_type(8))) short short8;
typedef __attribute__((ext_vector_type(4))) float f32x4;

DEV short f2bf(float x) {
  unsigned u = __float_as_uint(x);
  unsigned r = (u + 0x7fffu + ((u >> 16) & 1u)) >> 16;
  return (short)r;
}
DEV float bf2f(short x) {
  return __uint_as_float(((unsigned)(unsigned short)x) << 16);
}

DEV void gload_lds16(const void* g, void* l) {
  __builtin_amdgcn_global_load_lds((const __attribute__((address_space(1))) void*)g,
                                   (__attribute__((address_space(3))) void*)l, 16, 0, 0);
}

// ---------- fused projection GEMM, fp32 source: C = A_f32 @ W_f32^T -> bf16 ----------
// BM=128 BN=64 BK=64; 256 threads = 4 waves (2x2); wave tile 64x32 (4x2 frags of 16x16x32).
// A and W are read in fp32 and converted during reg-staging (fuses the old cvt kernel).
// Reg-staged: load float4 x2 per 16B-bf16 chunk -> f2bf -> ds_write_b128 at XOR-swizzled
// slot (slot s stored at s^(row&7); reader fetches (kk*4+lg)^(row&7) -> consistent).
// Loads for kt+1 are issued before the MFMA phase; consumed only at next convert ->
// HBM latency hides under barrier + MFMA + other waves (16 waves/CU).
// z selects (q,Wq),(k,Wk),(v,Wv). First 64 pre-swizzle blocks also zero Mb (512 KiB).
__global__ __launch_bounds__(256) void gemm_proj_f32(
    const float* __restrict__ q, const float* __restrict__ k, const float* __restrict__ v,
    const float* __restrict__ Wq, const float* __restrict__ Wk, const float* __restrict__ Wv,
    short* __restrict__ C, long strideC, float* __restrict__ Mb) {
  __shared__ short At[128 * 64];
  __shared__ short Bt[64 * 64];
  const int t = threadIdx.x;
  // XCD-chunked swizzle (grid = 16x32x3 = 1536 blocks, %8==0)
  const int nx = gridDim.x, ny = gridDim.y;
  int flat = blockIdx.x + nx * (blockIdx.y + ny * blockIdx.z);
  int nwg = nx * ny * gridDim.z;
  // Mb zero-init (kv_outer atomics need zeros; ws is poisoned 0xAA). 64 blocks x 8 KiB.
  if (flat < 64) {
    float4 z = {0.f, 0.f, 0.f, 0.f};
    float4* p = reinterpret_cast<float4*>(Mb) + (size_t)flat * 512 + t * 2;
    p[0] = z;
    p[1] = z;
  }
  int l2 = (flat & 7) * (nwg >> 3) + (flat >> 3);
  int colB = l2 % nx;
  int tmp = l2 / nx;
  int rowB = tmp % ny;
  int zB = tmp / ny;

  const float* Ab = zB == 0 ? q : zB == 1 ? k : v;
  const float* Wb = zB == 0 ? Wq : zB == 1 ? Wk : Wv;
  short* Cb = C + (size_t)zB * strideC;
  const int w = t >> 6;
  const int l = t & 63;
  const int lg = l >> 4, lr = l & 15;
  const int wm = w >> 1, wn = w & 1;
  const int rowBase = rowB * 128;
  const int colBase = colB * 64;

  f32x4 acc[4][2] = {};
  float4 ra[4][2], rw[2][2];

  // chunk geometry: c in [0,1024) A / [0,512) W; r=c>>3 (tile row), s=c&7 (16B k-slot)
#define LOAD_TILES(k0)                                                     \
  {                                                                        \
    _Pragma("unroll") for (int i = 0; i < 4; ++i) {                        \
      int c = w * 256 + i * 64 + l;                                        \
      int r = c >> 3, s = c & 7;                                           \
      const float* src = Ab + (size_t)(rowBase + r) * 1024 + (k0) + s * 8; \
      ra[i][0] = *reinterpret_cast<const float4*>(src);                    \
      ra[i][1] = *reinterpret_cast<const float4*>(src + 4);                \
    }                                                                      \
    _Pragma("unroll") for (int i = 0; i < 2; ++i) {                        \
      int c = w * 128 + i * 64 + l;                                        \
      int r = c >> 3, s = c & 7;                                           \
      const float* src = Wb + (size_t)(colBase + r) * 1024 + (k0) + s * 8; \
      rw[i][0] = *reinterpret_cast<const float4*>(src);                    \
      rw[i][1] = *reinterpret_cast<const float4*>(src + 4);                \
    }                                                                      \
  }

  LOAD_TILES(0);

  for (int kt = 0; kt < 16; ++kt) {
    __syncthreads();  // previous iter's LDS reads done
    // convert staged regs -> LDS (XOR-swizzled k-slot)
#pragma unroll
    for (int i = 0; i < 4; ++i) {
      int c = w * 256 + i * 64 + l;
      int r = c >> 3, s = c & 7;
      short8 o;
      o[0] = f2bf(ra[i][0].x); o[1] = f2bf(ra[i][0].y);
      o[2] = f2bf(ra[i][0].z); o[3] = f2bf(ra[i][0].w);
      o[4] = f2bf(ra[i][1].x); o[5] = f2bf(ra[i][1].y);
      o[6] = f2bf(ra[i][1].z); o[7] = f2bf(ra[i][1].w);
      *reinterpret_cast<short8*>(&At[r * 64 + ((s ^ (r & 7)) << 3)]) = o;
    }
#pragma unroll
    for (int i = 0; i < 2; ++i) {
      int c = w * 128 + i * 64 + l;
      int r = c >> 3, s = c & 7;
      short8 o;
      o[0] = f2bf(rw[i][0].x); o[1] = f2bf(rw[i][0].y);
      o[2] = f2bf(rw[i][0].z); o[3] = f2bf(rw[i][0].w);
      o[4] = f2bf(rw[i][1].x); o[5] = f2bf(rw[i][1].y);
      o[6] = f2bf(rw[i][1].z); o[7] = f2bf(rw[i][1].w);
      *reinterpret_cast<short8*>(&Bt[r * 64 + ((s ^ (r & 7)) << 3)]) = o;
    }
    if (kt < 15) LOAD_TILES((kt + 1) * 64);  // prefetch next tile into regs
    __syncthreads();  // LDS writes visible
#pragma unroll
    for (int kk = 0; kk < 2; ++kk) {
      short8 bfr[2];
#pragma unroll
      for (int n = 0; n < 2; ++n) {
        int br = wn * 32 + n * 16 + lr;
        int slot = (kk * 4 + lg) ^ (br & 7);
        bfr[n] = *reinterpret_cast<const short8*>(&Bt[br * 64 + slot * 8]);
      }
#pragma unroll
      for (int m = 0; m < 4; ++m) {
        int ar = wm * 64 + m * 16 + lr;
        int slot = (kk * 4 + lg) ^ (ar & 7);
        short8 afr = *reinterpret_cast<const short8*>(&At[ar * 64 + slot * 8]);
        acc[m][0] = __builtin_amdgcn_mfma_f32_16x16x32_bf16(afr, bfr[0], acc[m][0], 0, 0, 0);
        acc[m][1] = __builtin_amdgcn_mfma_f32_16x16x32_bf16(afr, bfr[1], acc[m][1], 0, 0, 0);
      }
    }
  }
#undef LOAD_TILES
  // epilogue: C/D layout col = lane&15, row = (lane>>4)*4 + j
#pragma unroll
  for (int m = 0; m < 4; ++m)
#pragma unroll
    for (int n = 0; n < 2; ++n) {
      int row0 = rowBase + wm * 64 + m * 16 + lg * 4;
      int col = colBase + wn * 32 + n * 16 + lr;
#pragma unroll
      for (int j = 0; j < 4; ++j)
        Cb[(size_t)(row0 + j) * 1024 + col] = f2bf(acc[m][n][j]);
    }
}

// ---------- bf16 MFMA GEMM, 128x64 tile (gload_lds path): C = A @ W^T ----------
// Same structure as proven R3/R4 kernel; used for the final GEMM (bf16 inputs).
template <typename OutT>
__global__ __launch_bounds__(256) void gemm_bt64(const short* __restrict__ A,
                                                 const short* __restrict__ W,
                                                 OutT* __restrict__ C,
                                                 long strideA, long strideW, long strideC) {
  __shared__ short At[128 * 64];
  __shared__ short Bt[64 * 64];
  const int nx = gridDim.x, ny = gridDim.y;
  int flat = blockIdx.x + nx * (blockIdx.y + ny * blockIdx.z);
  int nwg = nx * ny * gridDim.z;
  int l2 = (flat & 7) * (nwg >> 3) + (flat >> 3);
  int colB = l2 % nx;
  int tmp = l2 / nx;
  int rowB = tmp % ny;
  int zB = tmp / ny;

  const short* Ab = A + (size_t)zB * strideA;
  const short* Wb = W + (size_t)zB * strideW;
  OutT* Cb = C + (size_t)zB * strideC;
  const int t = threadIdx.x;
  const int w = t >> 6;
  const int l = t & 63;
  const int lg = l >> 4, lr = l & 15;
  const int wm = w >> 1, wn = w & 1;
  const int rowBase = rowB * 128;
  const int colBase = colB * 64;

  f32x4 acc[4][2] = {};

  for (int kt = 0; kt < 16; ++kt) {
    const int k0 = kt * 64;
    __syncthreads();
#pragma unroll
    for (int i = 0; i < 4; ++i) {
      int c = w * 256 + i * 64 + l;
      int r = c >> 3, s = c & 7;
      gload_lds16(Ab + (size_t)(rowBase + r) * 1024 + k0 + ((s ^ (r & 7)) << 3),
                  At + (size_t)c * 8);
    }
#pragma unroll
    for (int i = 0; i < 2; ++i) {
      int c = w * 128 + i * 64 + l;
      int r = c >> 3, s = c & 7;
      gload_lds16(Wb + (size_t)(colBase + r) * 1024 + k0 + ((s ^ (r & 7)) << 3),
                  Bt + (size_t)c * 8);
    }
    __syncthreads();
#pragma unroll
    for (int kk = 0; kk < 2; ++kk) {
      short8 bfr[2];
#pragma unroll
      for (int n = 0; n < 2; ++n) {
        int br = wn * 32 + n * 16 + lr;
        int slot = (kk * 4 + lg) ^ (br & 7);
        bfr[n] = *reinterpret_cast<const short8*>(&Bt[br * 64 + slot * 8]);
      }
#pragma unroll
      for (int m = 0; m < 4; ++m) {
        int ar = wm * 64 + m * 16 + lr;
        int slot = (kk * 4 + lg) ^ (ar & 7);
        short8 afr = *reinterpret_cast<const short8*>(&At[ar * 64 + slot * 8]);
        acc[m][0] = __builtin_amdgcn_mfma_f32_16x16x32_bf16(afr, bfr[0], acc[m][0], 0, 0, 0);
        acc[m][1] = __builtin_amdgcn_mfma_f32_16x16x32_bf16(afr, bfr[1], acc[m][1], 0, 0, 0);
      }
    }
  }
#pragma unroll
  for (int m = 0; m < 4; ++m)
#pragma unroll
    for (int n = 0; n < 2; ++n) {
      int row0 = rowBase + wm * 64 + m * 16 + lg * 4;
      int col = colBase + wn * 32 + n * 16 + lr;
#pragma unroll
      for (int j = 0; j < 4; ++j) {
        float v = acc[m][n][j];
        if constexpr (sizeof(OutT) == 2)
          Cb[(size_t)(row0 + j) * 1024 + col] = (OutT)f2bf(v);
        else
          Cb[(size_t)(row0 + j) * 1024 + col] = (OutT)v;
      }
    }
}

// ---------- M[b][h] = K_bh^T V_bh / 8  (fp32, split-S atomics; Mb pre-zeroed) ----------
__global__ __launch_bounds__(256) void kv_outer(const short* __restrict__ Kp,
                                                const short* __restrict__ Vp,
                                                float* __restrict__ Mb) {
  __shared__ float Ks[128][64];
  __shared__ float Vs[128][64];
  const int t = threadIdx.x;
  const int sc = blockIdx.x, h = blockIdx.y, b = blockIdx.z;
  const size_t base = ((size_t)(b * 2048 + sc * 128)) * 1024 + h * 64;
  for (int e = t; e < 128 * 64; e += 256) {
    int r = e >> 6, c = e & 63;
    size_t g = base + (size_t)r * 1024 + c;
    Ks[r][c] = bf2f(Kp[g]);
    Vs[r][c] = bf2f(Vp[g]);
  }
  __syncthreads();
  const int dp0 = (t >> 4) * 4, d0 = (t & 15) * 4;
  float acc[4][4] = {};
  for (int s = 0; s < 128; ++s) {
    float4 kv = *reinterpret_cast<const float4*>(&Ks[s][dp0]);
    float4 vv = *reinterpret_cast<const float4*>(&Vs[s][d0]);
    float ka[4] = {kv.x, kv.y, kv.z, kv.w};
    float va[4] = {vv.x, vv.y, vv.z, vv.w};
#pragma unroll
    for (int i = 0; i < 4; ++i)
#pragma unroll
      for (int j = 0; j < 4; ++j) acc[i][j] += ka[i] * va[j];
  }
  float* dst = Mb + (size_t)(b * 16 + h) * 4096;
#pragma unroll
  for (int i = 0; i < 4; ++i)
#pragma unroll
    for (int j = 0; j < 4; ++j)
      atomicAdd(&dst[(dp0 + i) * 64 + d0 + j], acc[i][j] * 0.125f);
}

// ---------- W2T[b][j][h*64+d'] = sum_d M_bh[d'][d] * Wo_f32[j][h*64+d]  (bf16 out) ----------
__global__ __launch_bounds__(256) void make_w2t(const float* __restrict__ Mb,
                                                const float* __restrict__ Wo,
                                                short* __restrict__ W2T) {
  __shared__ float Ms[64][65];
  __shared__ float Wos[64][64];
  const int t = threadIdx.x;
  const int jc = blockIdx.x, h = blockIdx.y, b = blockIdx.z;
  const float* Msrc = Mb + (size_t)(b * 16 + h) * 4096;
  for (int e = t; e < 4096; e += 256) {
    int r = e >> 6, c = e & 63;
    Ms[r][c] = Msrc[e];
    Wos[r][c] = Wo[(size_t)(jc * 64 + r) * 1024 + h * 64 + c];
  }
  __syncthreads();
  const int j0 = (t >> 4) * 4, p0 = (t & 15) * 4;
  float acc[4][4] = {};
  for (int d = 0; d < 64; ++d) {
    float wv[4], mv[4];
#pragma unroll
    for (int i = 0; i < 4; ++i) { wv[i] = Wos[j0 + i][d]; mv[i] = Ms[p0 + i][d]; }
#pragma unroll
    for (int i = 0; i < 4; ++i)
#pragma unroll
      for (int j2 = 0; j2 < 4; ++j2) acc[i][j2] += wv[i] * mv[j2];
  }
  short* dst = W2T + (size_t)b * 1048576;
#pragma unroll
  for (int i = 0; i < 4; ++i)
#pragma unroll
    for (int j2 = 0; j2 < 4; ++j2)
      dst[(size_t)(jc * 64 + j0 + i) * 1024 + h * 64 + p0 + j2] = f2bf(acc[i][j2]);
}

extern "C" void kernel_launch(void* const* d_in, const int* in_sizes, int n_in,
                              void* d_out, int out_size, void* d_ws, size_t ws_size,
                              hipStream_t stream) {
  const float* q  = (const float*)d_in[0];
  const float* k  = (const float*)d_in[1];
  const float* v  = (const float*)d_in[2];
  // d_in[3] = mask: no-op in the reference
  const float* Wq = (const float*)d_in[4];
  const float* Wk = (const float*)d_in[5];
  const float* Wv = (const float*)d_in[6];
  const float* Wo = (const float*)d_in[7];
  float* out = (float*)d_out;
  char* ws = (char*)d_ws;

  // workspace layout (~29 MiB)
  short* Pp = (short*)(ws);                   // 24 MiB: Qp,Kp,Vp bf16 contiguous
  short* Qp = Pp;
  short* Kp = Pp + (size_t)4194304;
  short* Vp = Pp + (size_t)8388608;
  float* Mb  = (float*)(ws + (24l << 20));    // 512 KiB
  short* W2T = (short*)(ws + (25l << 20));    // 4 MiB

  // 1) Q/K/V projections straight from fp32 (fused convert); also zeroes Mb.
  //    grid 16x32x3 = 1536 blocks.
  gemm_proj_f32<<<dim3(16, 32, 3), 256, 0, stream>>>(
      q, k, v, Wq, Wk, Wv, Pp, 4194304l, Mb);

  // 2) per-head K^T V / 8
  kv_outer<<<dim3(16, 16, 2), 256, 0, stream>>>(Kp, Vp, Mb);

  // 3) fold blockdiag(M) into Wo (reads fp32 Wo directly)
  make_w2t<<<dim3(16, 16, 2), 256, 0, stream>>>(Mb, Wo, W2T);

  // 4) out[b] = Qp[b] @ W2T[b]^T  (512 blocks)
  gemm_bt64<float><<<dim3(16, 16, 2), 256, 0, stream>>>(
      Qp, W2T, out, 2097152l, 1048576l, 2097152l);
}

// Round 6
// 210.178 us; speedup vs baseline: 1.0806x; 1.0806x over previous
//
#include <hip/hip_runtime.h>

#define DEV __device__ __forceinline__

typedef __attribute__((ext_vector_type(8))) short short8;
typedef __attribute__((ext_vector_type(4))) float f32x4;

DEV short f2bf(float x) {
  unsigned u = __float_as_uint(x);
  unsigned r = (u + 0x7fffu + ((u >> 16) & 1u)) >> 16;
  return (short)r;
}
DEV float bf2f(short x) {
  return __uint_as_float(((unsigned)(unsigned short)x) << 16);
}

DEV void gload_lds16(const void* g, void* l) {
  __builtin_amdgcn_global_load_lds((const __attribute__((address_space(1))) void*)g,
                                   (__attribute__((address_space(3))) void*)l, 16, 0, 0);
}

// ---------- fused fp32 -> bf16 convert (q,k,v,Wq,Wk,Wv) + zero-init of Mb ----------
// groups of 8: q,k,v = 524288 each; Wq,Wk,Wv = 131072 each (total 1966080),
// then 16384 zero-groups for Mb (131072 floats). Wo is NOT converted (make_w2t
// reads it fp32 directly).
__global__ __launch_bounds__(256) void cvt_all(
    const float* __restrict__ s0, const float* __restrict__ s1,
    const float* __restrict__ s2, const float* __restrict__ s3,
    const float* __restrict__ s4, const float* __restrict__ s5,
    short* __restrict__ d0, short* __restrict__ d1, short* __restrict__ d2,
    short* __restrict__ d3, short* __restrict__ d4, short* __restrict__ d5,
    float* __restrict__ Mb) {
  int g = blockIdx.x * 256 + threadIdx.x;
  if (g >= 1966080) {  // Mb zero-init (kv_outer atomics need zeros; ws is poisoned 0xAA)
    int off = g - 1966080;
    float4 z = {0.f, 0.f, 0.f, 0.f};
    float4* p = reinterpret_cast<float4*>(Mb) + (size_t)off * 2;
    p[0] = z;
    p[1] = z;
    return;
  }
  const float* s;
  short* d;
  int off;
  if (g < 524288) { s = s0; d = d0; off = g; }
  else if (g < 1048576) { s = s1; d = d1; off = g - 524288; }
  else if (g < 1572864) { s = s2; d = d2; off = g - 1048576; }
  else {
    int w2 = g - 1572864;
    int seg = w2 >> 17;
    off = w2 & 131071;
    s = seg == 0 ? s3 : seg == 1 ? s4 : s5;
    d = seg == 0 ? d3 : seg == 1 ? d4 : d5;
  }
  const float4* p = reinterpret_cast<const float4*>(s) + (size_t)off * 2;
  float4 a = p[0], b = p[1];
  short8 o;
  o[0] = f2bf(a.x); o[1] = f2bf(a.y); o[2] = f2bf(a.z); o[3] = f2bf(a.w);
  o[4] = f2bf(b.x); o[5] = f2bf(b.y); o[6] = f2bf(b.z); o[7] = f2bf(b.w);
  *reinterpret_cast<short8*>(d + (size_t)off * 8) = o;
}

// ---------- bf16 MFMA GEMM, 64x64 tile: C[M,1024] = A[M,1024] @ W[1024,1024]^T ----------
// BM=BN=BK=64; 256 threads = 4 waves (2x2); wave tile 32x32 (2x2 frags of 16x16x32).
// 16 KB LDS + <=64 VGPR (__launch_bounds__(256,8)) -> 8 blocks/CU = 32 waves/CU:
// 2x the residency of the 128x64 tile (VGPR-capped at 4 blocks), to hide the
// per-K-step vmcnt(0) barrier drain (latency-bound regime per R3: MfmaUtil 23%,
// occupancy 21%). gload_lds staging (m151: faster than reg-staging at these tiles).
// XCD-chunked swizzle: col-fastest within XCD chunk -> A row-panel L2-resident,
// W (2 MB/z) L2-resident. LDS [row][64] bf16, k-slot XOR-swizzle by (row&7):
// linear gload_lds dest + inverse-swizzled global src + same-swizzled ds_read.
template <typename OutT>
__global__ __launch_bounds__(256, 8) void gemm64(const short* __restrict__ A,
                                                 const short* __restrict__ W,
                                                 OutT* __restrict__ C,
                                                 long strideA, long strideW, long strideC) {
  __shared__ short At[64 * 64];
  __shared__ short Bt[64 * 64];
  const int nx = gridDim.x, ny = gridDim.y;
  int flat = blockIdx.x + nx * (blockIdx.y + ny * blockIdx.z);
  int nwg = nx * ny * gridDim.z;
  int l2 = (flat & 7) * (nwg >> 3) + (flat >> 3);  // grid %8==0 for all launches
  int colB = l2 % nx;
  int tmp = l2 / nx;
  int rowB = tmp % ny;
  int zB = tmp / ny;

  const short* Ab = A + (size_t)zB * strideA;
  const short* Wb = W + (size_t)zB * strideW;
  OutT* Cb = C + (size_t)zB * strideC;
  const int t = threadIdx.x;
  const int w = t >> 6;
  const int l = t & 63;
  const int lg = l >> 4, lr = l & 15;
  const int wm = w >> 1, wn = w & 1;
  const int rowBase = rowB * 64;
  const int colBase = colB * 64;

  f32x4 acc[2][2] = {};

  for (int kt = 0; kt < 16; ++kt) {
    const int k0 = kt * 64;
    __syncthreads();  // previous iter's LDS reads done
#pragma unroll
    for (int i = 0; i < 2; ++i) {  // A tile: 512 16B chunks, 2/thread
      int c = w * 128 + i * 64 + l;
      int r = c >> 3, s = c & 7;
      gload_lds16(Ab + (size_t)(rowBase + r) * 1024 + k0 + ((s ^ (r & 7)) << 3),
                  At + (size_t)c * 8);
    }
#pragma unroll
    for (int i = 0; i < 2; ++i) {  // B tile: 512 chunks, 2/thread
      int c = w * 128 + i * 64 + l;
      int r = c >> 3, s = c & 7;
      gload_lds16(Wb + (size_t)(colBase + r) * 1024 + k0 + ((s ^ (r & 7)) << 3),
                  Bt + (size_t)c * 8);
    }
    __syncthreads();  // vmcnt(0) drained before barrier -> tiles ready
#pragma unroll
    for (int kk = 0; kk < 2; ++kk) {
      short8 afr[2], bfr[2];
#pragma unroll
      for (int m = 0; m < 2; ++m) {
        int ar = wm * 32 + m * 16 + lr;
        int slot = (kk * 4 + lg) ^ (ar & 7);
        afr[m] = *reinterpret_cast<const short8*>(&At[ar * 64 + slot * 8]);
      }
#pragma unroll
      for (int n = 0; n < 2; ++n) {
        int br = wn * 32 + n * 16 + lr;
        int slot = (kk * 4 + lg) ^ (br & 7);
        bfr[n] = *reinterpret_cast<const short8*>(&Bt[br * 64 + slot * 8]);
      }
#pragma unroll
      for (int m = 0; m < 2; ++m)
#pragma unroll
        for (int n = 0; n < 2; ++n)
          acc[m][n] = __builtin_amdgcn_mfma_f32_16x16x32_bf16(afr[m], bfr[n], acc[m][n], 0, 0, 0);
    }
  }
  // epilogue: C/D layout col = lane&15, row = (lane>>4)*4 + j
#pragma unroll
  for (int m = 0; m < 2; ++m)
#pragma unroll
    for (int n = 0; n < 2; ++n) {
      int row0 = rowBase + wm * 32 + m * 16 + lg * 4;
      int col = colBase + wn * 32 + n * 16 + lr;
#pragma unroll
      for (int j = 0; j < 4; ++j) {
        float v = acc[m][n][j];
        if constexpr (sizeof(OutT) == 2)
          Cb[(size_t)(row0 + j) * 1024 + col] = (OutT)f2bf(v);
        else
          Cb[(size_t)(row0 + j) * 1024 + col] = (OutT)v;
      }
    }
}

// ---------- M[b][h] = K_bh^T V_bh / 8  (fp32, split-S atomics; Mb pre-zeroed) ----------
__global__ __launch_bounds__(256) void kv_outer(const short* __restrict__ Kp,
                                                const short* __restrict__ Vp,
                                                float* __restrict__ Mb) {
  __shared__ float Ks[128][64];
  __shared__ float Vs[128][64];
  const int t = threadIdx.x;
  const int sc = blockIdx.x, h = blockIdx.y, b = blockIdx.z;
  const size_t base = ((size_t)(b * 2048 + sc * 128)) * 1024 + h * 64;
  for (int e = t; e < 128 * 64; e += 256) {
    int r = e >> 6, c = e & 63;
    size_t g = base + (size_t)r * 1024 + c;
    Ks[r][c] = bf2f(Kp[g]);
    Vs[r][c] = bf2f(Vp[g]);
  }
  __syncthreads();
  const int dp0 = (t >> 4) * 4, d0 = (t & 15) * 4;
  float acc[4][4] = {};
  for (int s = 0; s < 128; ++s) {
    float4 kv = *reinterpret_cast<const float4*>(&Ks[s][dp0]);
    float4 vv = *reinterpret_cast<const float4*>(&Vs[s][d0]);
    float ka[4] = {kv.x, kv.y, kv.z, kv.w};
    float va[4] = {vv.x, vv.y, vv.z, vv.w};
#pragma unroll
    for (int i = 0; i < 4; ++i)
#pragma unroll
      for (int j = 0; j < 4; ++j) acc[i][j] += ka[i] * va[j];
  }
  float* dst = Mb + (size_t)(b * 16 + h) * 4096;
#pragma unroll
  for (int i = 0; i < 4; ++i)
#pragma unroll
    for (int j = 0; j < 4; ++j)
      atomicAdd(&dst[(dp0 + i) * 64 + d0 + j], acc[i][j] * 0.125f);
}

// ---------- W2T[b][j][h*64+d'] = sum_d M_bh[d'][d] * Wo_f32[j][h*64+d]  (bf16 out) ----------
__global__ __launch_bounds__(256) void make_w2t(const float* __restrict__ Mb,
                                                const float* __restrict__ Wo,
                                                short* __restrict__ W2T) {
  __shared__ float Ms[64][65];
  __shared__ float Wos[64][64];
  const int t = threadIdx.x;
  const int jc = blockIdx.x, h = blockIdx.y, b = blockIdx.z;
  const float* Msrc = Mb + (size_t)(b * 16 + h) * 4096;
  for (int e = t; e < 4096; e += 256) {
    int r = e >> 6, c = e & 63;
    Ms[r][c] = Msrc[e];
    Wos[r][c] = Wo[(size_t)(jc * 64 + r) * 1024 + h * 64 + c];
  }
  __syncthreads();
  const int j0 = (t >> 4) * 4, p0 = (t & 15) * 4;
  float acc[4][4] = {};
  for (int d = 0; d < 64; ++d) {
    float wv[4], mv[4];
#pragma unroll
    for (int i = 0; i < 4; ++i) { wv[i] = Wos[j0 + i][d]; mv[i] = Ms[p0 + i][d]; }
#pragma unroll
    for (int i = 0; i < 4; ++i)
#pragma unroll
      for (int j2 = 0; j2 < 4; ++j2) acc[i][j2] += wv[i] * mv[j2];
  }
  short* dst = W2T + (size_t)b * 1048576;
#pragma unroll
  for (int i = 0; i < 4; ++i)
#pragma unroll
    for (int j2 = 0; j2 < 4; ++j2)
      dst[(size_t)(jc * 64 + j0 + i) * 1024 + h * 64 + p0 + j2] = f2bf(acc[i][j2]);
}

extern "C" void kernel_launch(void* const* d_in, const int* in_sizes, int n_in,
                              void* d_out, int out_size, void* d_ws, size_t ws_size,
                              hipStream_t stream) {
  const float* q  = (const float*)d_in[0];
  const float* k  = (const float*)d_in[1];
  const float* v  = (const float*)d_in[2];
  // d_in[3] = mask: no-op in the reference
  const float* Wq = (const float*)d_in[4];
  const float* Wk = (const float*)d_in[5];
  const float* Wv = (const float*)d_in[6];
  const float* Wo = (const float*)d_in[7];
  float* out = (float*)d_out;
  char* ws = (char*)d_ws;

  // workspace layout (~60 MiB)
  short* qkv = (short*)(ws);                  // 24 MiB: q,k,v bf16 contiguous (4M elems each)
  short* qb = qkv;
  short* kb = qkv + (size_t)4194304;
  short* vb = qkv + (size_t)8388608;
  short* wb = (short*)(ws + (24l << 20));     // 6 MiB: Wq,Wk,Wv bf16 (1M elems each)
  short* wqb = wb;
  short* wkb = wb + 1048576;
  short* wvb = wb + 2097152;
  short* Pp = (short*)(ws + (30l << 20));     // 24 MiB: Qp,Kp,Vp bf16 contiguous
  short* Qp = Pp;
  short* Kp = Pp + (size_t)4194304;
  short* Vp = Pp + (size_t)8388608;
  float* Mb  = (float*)(ws + (54l << 20));    // 512 KiB
  short* W2T = (short*)(ws + (55l << 20));    // 4 MiB

  // 1) convert q,k,v,Wq,Wk,Wv to bf16 + zero Mb (1966080 cvt + 16384 zero groups)
  cvt_all<<<7744, 256, 0, stream>>>(q, k, v, Wq, Wk, Wv,
                                    qb, kb, vb, wqb, wkb, wvb, Mb);

  // 2) Q/K/V projections, one z-batched launch: 16x64x3 = 3072 blocks (8/CU resident)
  gemm64<short><<<dim3(16, 64, 3), 256, 0, stream>>>(
      qkv, wb, Pp, 4194304l, 1048576l, 4194304l);

  // 3) per-head K^T V / 8
  kv_outer<<<dim3(16, 16, 2), 256, 0, stream>>>(Kp, Vp, Mb);

  // 4) fold blockdiag(M) into Wo (reads fp32 Wo directly)
  make_w2t<<<dim3(16, 16, 2), 256, 0, stream>>>(Mb, Wo, W2T);

  // 5) out[b] = Qp[b] @ W2T[b]^T  (16x32x2 = 1024 blocks)
  gemm64<float><<<dim3(16, 32, 2), 256, 0, stream>>>(
      Qp, W2T, out, 2097152l, 1048576l, 2097152l);
}